// Round 3
// baseline (368.110 us; speedup 1.0000x reference)
//
#include <hip/hip_runtime.h>
#include <hip/hip_bf16.h>

typedef __hip_bfloat16 bf16;
typedef __attribute__((ext_vector_type(8))) short short8;
typedef __attribute__((ext_vector_type(4))) float f32x4;

#define B_    8192
#define C_    64
#define NTOT  524288            // B_*C_
#define OUT_W_OFF    67108864   // B_*B_
#define OUT_DATA_OFF (OUT_W_OFF + NTOT)
#define OUT_XN_OFF   (OUT_DATA_OFF + NTOT)
#define NRED  256               // reduce grid: must match partials layout

// ---------------- Kernel 1: per-block partial sum/sumsq (NO atomics, NO memset) --
__global__ __launch_bounds__(256) void reduce_kernel(const float* __restrict__ pred,
                                                     const float* __restrict__ imfs,
                                                     float* __restrict__ partials) {
    float s = 0.f, s2 = 0.f;
    int tid = blockIdx.x * blockDim.x + threadIdx.x;
    int stride = gridDim.x * blockDim.x;
    const f32x4* p4 = (const f32x4*)pred;
    const f32x4* i4 = (const f32x4*)imfs;
    for (int i = tid; i < B_ / 4; i += stride) {
        f32x4 v = p4[i];
        s += v.x + v.y + v.z + v.w;
        s2 += v.x * v.x + v.y * v.y + v.z * v.z + v.w * v.w;
    }
    for (int i = tid; i < (B_ * (C_ - 1)) / 4; i += stride) {
        f32x4 v = i4[i];
        s += v.x + v.y + v.z + v.w;
        s2 += v.x * v.x + v.y * v.y + v.z * v.z + v.w * v.w;
    }
    #pragma unroll
    for (int off = 32; off > 0; off >>= 1) {
        s  += __shfl_down(s,  off, 64);
        s2 += __shfl_down(s2, off, 64);
    }
    __shared__ float ls[4], ls2[4];
    int wv = threadIdx.x >> 6, ln = threadIdx.x & 63;
    if (ln == 0) { ls[wv] = s; ls2[wv] = s2; }
    __syncthreads();
    if (threadIdx.x == 0) {
        float a = 0.f, b = 0.f;
        for (int i = 0; i < 4; i++) { a += ls[i]; b += ls2[i]; }
        partials[2 * blockIdx.x]     = a;
        partials[2 * blockIdx.x + 1] = b;
    }
}

// ---------------- Kernel 2: per-row pipeline, ONE WAVE PER ROW, no barriers ------
__global__ __launch_bounds__(256) void rows_kernel(
    const float* __restrict__ pred, const float* __restrict__ imfs,
    const float* __restrict__ rev_w, const float* __restrict__ rev_b,
    const float* __restrict__ ca_w1, const float* __restrict__ ca_b1,
    const float* __restrict__ ca_w2, const float* __restrict__ ca_b2,
    const float* __restrict__ conv1_w, const float* __restrict__ conv1_b,
    const float* __restrict__ bn1_g, const float* __restrict__ bn1_b,
    const float* __restrict__ bn1_m, const float* __restrict__ bn1_v,
    const float* __restrict__ conv2_w, const float* __restrict__ conv2_b,
    const float* __restrict__ bn2_g, const float* __restrict__ bn2_b,
    const float* __restrict__ bn2_m, const float* __restrict__ bn2_v,
    const float* __restrict__ partials,
    float* __restrict__ out_w, float* __restrict__ out_data,
    float* __restrict__ out_xn,
    bf16* __restrict__ dhi, bf16* __restrict__ whi) {

    __shared__ float w1s[16 * 65];   // ca_w1[j][c]  at j*65+c
    __shared__ float w2s[64 * 17];   // ca_w2[c][j]  at c*17+j
    __shared__ float c1s[16 * 65];   // conv1 center tap [j][c]
    __shared__ float c2s[64 * 17];   // conv2 center tap [c][j]
    __shared__ float xnb[4][64];     // per-wave row buffer (wave-private)
    __shared__ float h1b[4][16];     // per-wave hidden buffer (wave-private)

    for (int i = threadIdx.x; i < 1024; i += 256) {
        int j = i >> 6, c = i & 63;
        w1s[j * 65 + c] = ca_w1[i];
        c1s[j * 65 + c] = conv1_w[i * 7 + 3];
    }
    for (int i = threadIdx.x; i < 1024; i += 256) {
        int c = i >> 4, j = i & 15;
        w2s[c * 17 + j] = ca_w2[i];
        c2s[c * 17 + j] = conv2_w[i * 7 + 3];
    }
    __syncthreads();

    const int c   = threadIdx.x & 63;
    const int wv  = threadIdx.x >> 6;
    const int jj  = c & 15;
    const int q16 = (c >> 4) * 16;

    // prologue: self-reduce the 256 {s,s2} partials (512 floats) in-wave.
    {
        const f32x4* pp = (const f32x4*)partials;   // 128 vectors
        f32x4 v0 = pp[c];
        f32x4 v1 = pp[64 + c];
        float s  = v0.x + v0.z + v1.x + v1.z;
        float s2 = v0.y + v0.w + v1.y + v1.w;
        #pragma unroll
        for (int off = 32; off > 0; off >>= 1) {
            s  += __shfl_xor(s,  off, 64);
            s2 += __shfl_xor(s2, off, 64);
        }
        xnb[wv][0] = s;
        xnb[wv][1] = s2;
    }
    __builtin_amdgcn_wave_barrier();
    const float inv_n = 1.0f / (float)NTOT;
    const float mu   = xnb[wv][0] * inv_n;
    const float var  = xnb[wv][1] * inv_n - mu * mu;
    const float stdv = sqrtf(var + 1e-5f);
    const float istd = 1.0f / stdv;
    __builtin_amdgcn_wave_barrier();

    const float revw = rev_w[c], revb = rev_b[c];
    const float cab2 = ca_b2[c], c2b = conv2_b[c];
    const float bn2s = bn2_g[c] * rsqrtf(bn2_v[c] + 1e-5f);
    const float bn2h = bn2_b[c] - bn2_m[c] * bn2s;
    const float cab1 = ca_b1[jj], c1b = conv1_b[jj];
    const float bn1s = bn1_g[jj] * rsqrtf(bn1_v[jj] + 1e-5f);
    const float bn1h = bn1_b[jj] - bn1_m[jj] * bn1s;

    const int gw = blockIdx.x * 4 + wv;
    for (int row = gw; row < B_; row += 2048) {
        float d = (c == 0) ? pred[row] : imfs[row * 63 + c - 1];
        out_data[row * 64 + c] = d;
        dhi[row * 64 + c] = __float2bfloat16(d);
        float xn = (d - mu) * istd * revw + revb;
        out_xn[row * 64 + c] = xn;
        xnb[wv][c] = xn;
        __builtin_amdgcn_wave_barrier();
        float p1 = 0.f;
        #pragma unroll
        for (int i = 0; i < 16; i++) p1 += w1s[jj * 65 + q16 + i] * xnb[wv][q16 + i];
        p1 += __shfl_xor(p1, 16, 64);
        p1 += __shfl_xor(p1, 32, 64);
        float y = fmaxf(p1 + cab1, 0.f);
        if (c < 16) h1b[wv][c] = y;
        __builtin_amdgcn_wave_barrier();
        float att = cab2;
        #pragma unroll
        for (int j = 0; j < 16; j++) att += w2s[c * 17 + j] * h1b[wv][j];
        float x = xn * att;
        xnb[wv][c] = x;
        __builtin_amdgcn_wave_barrier();
        float p2 = 0.f;
        #pragma unroll
        for (int i = 0; i < 16; i++) p2 += c1s[jj * 65 + q16 + i] * xnb[wv][q16 + i];
        p2 += __shfl_xor(p2, 16, 64);
        p2 += __shfl_xor(p2, 32, 64);
        float t = fmaxf((p2 + c1b) * bn1s + bn1h, 0.f);
        if (c < 16) h1b[wv][c] = t;
        __builtin_amdgcn_wave_barrier();
        float v = c2b;
        #pragma unroll
        for (int j = 0; j < 16; j++) v += c2s[c * 17 + j] * h1b[wv][j];
        v = v * bn2s + bn2h;
        float sg = 1.0f / (1.0f + __expf(-v));
        float ov = x * sg;
        float wval = (ov - revb) / (revw + 1e-10f) * stdv + mu;
        out_w[row * 64 + c] = wval;
        whi[row * 64 + c] = __float2bfloat16(wval);
        __builtin_amdgcn_wave_barrier();
    }
}

// ---------------- Kernel 3: recon = data @ w^T  (8192x8192, K=64) ---------------
// Operand-swapped streaming GEMM + register software pipeline.
// KEY: vmcnt counts loads AND stores in one FIFO. If loads(t+1) are issued after
// store(t), the wait for those loads forces every older NT store to complete to
// HBM (~900cy) -> latency serialization (~1.7 TB/s observed). Pipeline batches
// of 4 t's with issue order loads(b+1) -> MFMA(b) -> stores(b): the MFMA wait
// then tolerates {stores(b-1), loads(b+1)} outstanding and never drains stores.
__global__ __launch_bounds__(256, 4) void gemm_kernel(
    const bf16* __restrict__ dhi, const bf16* __restrict__ whi,
    float* __restrict__ out) {

    const int wid  = (blockIdx.x << 2) + (threadIdx.x >> 6);   // 0..8191
    const int lane = threadIdx.x & 63;
    const int m    = lane & 15;
    const int q    = lane >> 4;

    const int b0 = (wid >> 4) * 16;     // output-row group base
    const int h0 = (wid & 15) * 512;    // output-col chunk base

    const short* dptr = (const short*)dhi;
    const short* wptr = (const short*)whi;

    // B-operand fragments (data rows -> output rows), loaded once per wave
    short8 d0 = *(const short8*)(dptr + (b0 + m) * 64 + q * 8);
    short8 d1 = *(const short8*)(dptr + (b0 + m) * 64 + q * 8 + 32);

    float* orow = out + (long)(b0 + m) * B_ + h0 + q * 4;
    const short* abase = wptr + (h0 + m) * 64 + q * 8;   // A rows walk h0+t*16+m

    short8 ca0[4], ca1[4], na0[4], na1[4];
    #pragma unroll
    for (int i = 0; i < 4; i++) {
        ca0[i] = *(const short8*)(abase + i * 16 * 64);
        ca1[i] = *(const short8*)(abase + i * 16 * 64 + 32);
    }

    #pragma unroll
    for (int bb = 0; bb < 8; bb++) {
        // 1) issue NEXT batch's A-loads first (before any store of this batch)
        if (bb < 7) {
            #pragma unroll
            for (int i = 0; i < 4; i++) {
                na0[i] = *(const short8*)(abase + ((bb + 1) * 4 + i) * 16 * 64);
                na1[i] = *(const short8*)(abase + ((bb + 1) * 4 + i) * 16 * 64 + 32);
            }
        }
        // 2) compute current batch (waits only on its own loads, issued last iter)
        // 3) store current batch (fire-and-forget NT; never waited on)
        #pragma unroll
        for (int i = 0; i < 4; i++) {
            f32x4 acc = {0.f, 0.f, 0.f, 0.f};
            acc = __builtin_amdgcn_mfma_f32_16x16x32_bf16(ca0[i], d0, acc, 0, 0, 0);
            acc = __builtin_amdgcn_mfma_f32_16x16x32_bf16(ca1[i], d1, acc, 0, 0, 0);
            // D layout: col(lane&15)=data row m, row(q*4+r)=w row -> consecutive cols
            __builtin_nontemporal_store(acc, (f32x4*)(orow + (bb * 4 + i) * 16));
        }
        if (bb < 7) {
            #pragma unroll
            for (int i = 0; i < 4; i++) { ca0[i] = na0[i]; ca1[i] = na1[i]; }
        }
    }
}

extern "C" void kernel_launch(void* const* d_in, const int* in_sizes, int n_in,
                              void* d_out, int out_size, void* d_ws, size_t ws_size,
                              hipStream_t stream) {
    const float* pred    = (const float*)d_in[0];
    const float* imfs    = (const float*)d_in[1];
    const float* rev_w   = (const float*)d_in[2];
    const float* rev_b   = (const float*)d_in[3];
    const float* ca_w1   = (const float*)d_in[4];
    const float* ca_b1   = (const float*)d_in[5];
    const float* ca_w2   = (const float*)d_in[6];
    const float* ca_b2   = (const float*)d_in[7];
    const float* conv1_w = (const float*)d_in[8];
    const float* conv1_b = (const float*)d_in[9];
    const float* bn1_g   = (const float*)d_in[10];
    const float* bn1_b   = (const float*)d_in[11];
    const float* bn1_m   = (const float*)d_in[12];
    const float* bn1_v   = (const float*)d_in[13];
    const float* conv2_w = (const float*)d_in[14];
    const float* conv2_b = (const float*)d_in[15];
    const float* bn2_g   = (const float*)d_in[16];
    const float* bn2_b   = (const float*)d_in[17];
    const float* bn2_m   = (const float*)d_in[18];
    const float* bn2_v   = (const float*)d_in[19];

    float* out      = (float*)d_out;
    float* partials = (float*)d_ws;                    // 256 blocks x {s,s2} = 2KB
    bf16*  dhi      = (bf16*)((char*)d_ws + 2048);
    bf16*  whi      = dhi + NTOT;

    reduce_kernel<<<NRED, 256, 0, stream>>>(pred, imfs, partials);
    rows_kernel<<<512, 256, 0, stream>>>(pred, imfs, rev_w, rev_b, ca_w1, ca_b1,
                                         ca_w2, ca_b2, conv1_w, conv1_b,
                                         bn1_g, bn1_b, bn1_m, bn1_v,
                                         conv2_w, conv2_b, bn2_g, bn2_b, bn2_m, bn2_v,
                                         partials,
                                         out + OUT_W_OFF, out + OUT_DATA_OFF,
                                         out + OUT_XN_OFF, dhi, whi);
    gemm_kernel<<<2048, 256, 0, stream>>>(dhi, whi, out);
}

// Round 4
// 348.162 us; speedup vs baseline: 1.0573x; 1.0573x over previous
//
#include <hip/hip_runtime.h>
#include <hip/hip_bf16.h>

typedef __hip_bfloat16 bf16;
typedef __attribute__((ext_vector_type(8))) short short8;
typedef __attribute__((ext_vector_type(4))) float f32x4;

#define B_    8192
#define C_    64
#define NTOT  524288            // B_*C_
#define OUT_W_OFF    67108864   // B_*B_
#define OUT_DATA_OFF (OUT_W_OFF + NTOT)
#define OUT_XN_OFF   (OUT_DATA_OFF + NTOT)
#define NRED  256               // reduce grid: must match partials layout

// ---------------- Kernel 1: per-block partial sum/sumsq (NO atomics, NO memset) --
__global__ __launch_bounds__(256) void reduce_kernel(const float* __restrict__ pred,
                                                     const float* __restrict__ imfs,
                                                     float* __restrict__ partials) {
    float s = 0.f, s2 = 0.f;
    int tid = blockIdx.x * blockDim.x + threadIdx.x;
    int stride = gridDim.x * blockDim.x;
    const f32x4* p4 = (const f32x4*)pred;
    const f32x4* i4 = (const f32x4*)imfs;
    for (int i = tid; i < B_ / 4; i += stride) {
        f32x4 v = p4[i];
        s += v.x + v.y + v.z + v.w;
        s2 += v.x * v.x + v.y * v.y + v.z * v.z + v.w * v.w;
    }
    for (int i = tid; i < (B_ * (C_ - 1)) / 4; i += stride) {
        f32x4 v = i4[i];
        s += v.x + v.y + v.z + v.w;
        s2 += v.x * v.x + v.y * v.y + v.z * v.z + v.w * v.w;
    }
    #pragma unroll
    for (int off = 32; off > 0; off >>= 1) {
        s  += __shfl_down(s,  off, 64);
        s2 += __shfl_down(s2, off, 64);
    }
    __shared__ float ls[4], ls2[4];
    int wv = threadIdx.x >> 6, ln = threadIdx.x & 63;
    if (ln == 0) { ls[wv] = s; ls2[wv] = s2; }
    __syncthreads();
    if (threadIdx.x == 0) {
        float a = 0.f, b = 0.f;
        for (int i = 0; i < 4; i++) { a += ls[i]; b += ls2[i]; }
        partials[2 * blockIdx.x]     = a;
        partials[2 * blockIdx.x + 1] = b;
    }
}

// ---------------- Kernel 2: per-row pipeline, ONE WAVE PER ROW, no barriers ------
__global__ __launch_bounds__(256) void rows_kernel(
    const float* __restrict__ pred, const float* __restrict__ imfs,
    const float* __restrict__ rev_w, const float* __restrict__ rev_b,
    const float* __restrict__ ca_w1, const float* __restrict__ ca_b1,
    const float* __restrict__ ca_w2, const float* __restrict__ ca_b2,
    const float* __restrict__ conv1_w, const float* __restrict__ conv1_b,
    const float* __restrict__ bn1_g, const float* __restrict__ bn1_b,
    const float* __restrict__ bn1_m, const float* __restrict__ bn1_v,
    const float* __restrict__ conv2_w, const float* __restrict__ conv2_b,
    const float* __restrict__ bn2_g, const float* __restrict__ bn2_b,
    const float* __restrict__ bn2_m, const float* __restrict__ bn2_v,
    const float* __restrict__ partials,
    float* __restrict__ out_w, float* __restrict__ out_data,
    float* __restrict__ out_xn,
    bf16* __restrict__ dhi, bf16* __restrict__ whi) {

    __shared__ float w1s[16 * 65];   // ca_w1[j][c]  at j*65+c
    __shared__ float w2s[64 * 17];   // ca_w2[c][j]  at c*17+j
    __shared__ float c1s[16 * 65];   // conv1 center tap [j][c]
    __shared__ float c2s[64 * 17];   // conv2 center tap [c][j]
    __shared__ float xnb[4][64];     // per-wave row buffer (wave-private)
    __shared__ float h1b[4][16];     // per-wave hidden buffer (wave-private)

    for (int i = threadIdx.x; i < 1024; i += 256) {
        int j = i >> 6, c = i & 63;
        w1s[j * 65 + c] = ca_w1[i];
        c1s[j * 65 + c] = conv1_w[i * 7 + 3];
    }
    for (int i = threadIdx.x; i < 1024; i += 256) {
        int c = i >> 4, j = i & 15;
        w2s[c * 17 + j] = ca_w2[i];
        c2s[c * 17 + j] = conv2_w[i * 7 + 3];
    }
    __syncthreads();

    const int c   = threadIdx.x & 63;
    const int wv  = threadIdx.x >> 6;
    const int jj  = c & 15;
    const int q16 = (c >> 4) * 16;

    // prologue: self-reduce the 256 {s,s2} partials (512 floats) in-wave.
    {
        const f32x4* pp = (const f32x4*)partials;   // 128 vectors
        f32x4 v0 = pp[c];
        f32x4 v1 = pp[64 + c];
        float s  = v0.x + v0.z + v1.x + v1.z;
        float s2 = v0.y + v0.w + v1.y + v1.w;
        #pragma unroll
        for (int off = 32; off > 0; off >>= 1) {
            s  += __shfl_xor(s,  off, 64);
            s2 += __shfl_xor(s2, off, 64);
        }
        xnb[wv][0] = s;
        xnb[wv][1] = s2;
    }
    __builtin_amdgcn_wave_barrier();
    const float inv_n = 1.0f / (float)NTOT;
    const float mu   = xnb[wv][0] * inv_n;
    const float var  = xnb[wv][1] * inv_n - mu * mu;
    const float stdv = sqrtf(var + 1e-5f);
    const float istd = 1.0f / stdv;
    __builtin_amdgcn_wave_barrier();

    const float revw = rev_w[c], revb = rev_b[c];
    const float cab2 = ca_b2[c], c2b = conv2_b[c];
    const float bn2s = bn2_g[c] * rsqrtf(bn2_v[c] + 1e-5f);
    const float bn2h = bn2_b[c] - bn2_m[c] * bn2s;
    const float cab1 = ca_b1[jj], c1b = conv1_b[jj];
    const float bn1s = bn1_g[jj] * rsqrtf(bn1_v[jj] + 1e-5f);
    const float bn1h = bn1_b[jj] - bn1_m[jj] * bn1s;

    const int gw = blockIdx.x * 4 + wv;
    for (int row = gw; row < B_; row += 2048) {
        float d = (c == 0) ? pred[row] : imfs[row * 63 + c - 1];
        out_data[row * 64 + c] = d;
        dhi[row * 64 + c] = __float2bfloat16(d);
        float xn = (d - mu) * istd * revw + revb;
        out_xn[row * 64 + c] = xn;
        xnb[wv][c] = xn;
        __builtin_amdgcn_wave_barrier();
        float p1 = 0.f;
        #pragma unroll
        for (int i = 0; i < 16; i++) p1 += w1s[jj * 65 + q16 + i] * xnb[wv][q16 + i];
        p1 += __shfl_xor(p1, 16, 64);
        p1 += __shfl_xor(p1, 32, 64);
        float y = fmaxf(p1 + cab1, 0.f);
        if (c < 16) h1b[wv][c] = y;
        __builtin_amdgcn_wave_barrier();
        float att = cab2;
        #pragma unroll
        for (int j = 0; j < 16; j++) att += w2s[c * 17 + j] * h1b[wv][j];
        float x = xn * att;
        xnb[wv][c] = x;
        __builtin_amdgcn_wave_barrier();
        float p2 = 0.f;
        #pragma unroll
        for (int i = 0; i < 16; i++) p2 += c1s[jj * 65 + q16 + i] * xnb[wv][q16 + i];
        p2 += __shfl_xor(p2, 16, 64);
        p2 += __shfl_xor(p2, 32, 64);
        float t = fmaxf((p2 + c1b) * bn1s + bn1h, 0.f);
        if (c < 16) h1b[wv][c] = t;
        __builtin_amdgcn_wave_barrier();
        float v = c2b;
        #pragma unroll
        for (int j = 0; j < 16; j++) v += c2s[c * 17 + j] * h1b[wv][j];
        v = v * bn2s + bn2h;
        float sg = 1.0f / (1.0f + __expf(-v));
        float ov = x * sg;
        float wval = (ov - revb) / (revw + 1e-10f) * stdv + mu;
        out_w[row * 64 + c] = wval;
        whi[row * 64 + c] = __float2bfloat16(wval);
        __builtin_amdgcn_wave_barrier();
    }
}

// ---------------- Kernel 3: recon = data @ w^T  (8192x8192, K=64) ---------------
// Persistent-wave, output-sweeping GEMM. 4096 waves (1024 blocks, ALL resident
// at 4 blocks/CU). Each wave owns a FIXED 16-col chunk (A-frags of whi loaded
// ONCE, 8 VGPR) and sweeps row-groups rg = rg0 + 8*it in near-lockstep.
// => at any instant the grid's stores cover ~8 row-group stripes (~4 MB moving
// window) instead of a ~130 MB scattered footprint -> DRAM row-buffer locality
// like the 6.4 TB/s fill, which is the same trick grid-stride fills use.
// ~50 VGPR: no spill risk under (256,4). Numerics identical to prior rounds.
__global__ __launch_bounds__(256, 4) void gemm_kernel(
    const bf16* __restrict__ dhi, const bf16* __restrict__ whi,
    float* __restrict__ out) {

    const int wid  = (blockIdx.x << 2) + (threadIdx.x >> 6);   // 0..4095
    const int lane = threadIdx.x & 63;
    const int m    = lane & 15;
    const int q    = lane >> 4;

    const int cc   = wid & 511;          // fixed col chunk: cols [cc*16, cc*16+16)
    const int rg0  = wid >> 9;           // starting row-group 0..7

    const short* dptr = (const short*)dhi;
    const short* wptr = (const short*)whi;

    // A fragments (whi rows cc*16+m), fixed for the wave's lifetime
    short8 a0 = *(const short8*)(wptr + (cc * 16 + m) * 64 + q * 8);
    short8 a1 = *(const short8*)(wptr + (cc * 16 + m) * 64 + q * 8 + 32);

    const short* dbase = dptr + m * 64 + q * 8;          // + rg*16*64
    float* obase = out + (long)m * B_ + cc * 16 + q * 4; // + rg*16*B_

    // preload first row-group's B fragment
    short8 d0 = *(const short8*)(dbase + rg0 * 1024);
    short8 d1 = *(const short8*)(dbase + rg0 * 1024 + 32);

    #pragma unroll 4
    for (int it = 0; it < 64; it++) {
        const int rg = rg0 + it * 8;
        // prefetch next row-group's B BEFORE this iteration's store, so the
        // wait for it need not drain the outstanding store (vmcnt is in-order)
        short8 nd0, nd1;
        if (it < 63) {
            nd0 = *(const short8*)(dbase + (rg + 8) * 1024);
            nd1 = *(const short8*)(dbase + (rg + 8) * 1024 + 32);
        }
        f32x4 acc = {0.f, 0.f, 0.f, 0.f};
        acc = __builtin_amdgcn_mfma_f32_16x16x32_bf16(a0, d0, acc, 0, 0, 0);
        acc = __builtin_amdgcn_mfma_f32_16x16x32_bf16(a1, d1, acc, 0, 0, 0);
        // D layout: out_row = rg*16 + m, out_cols = cc*16 + q*4 + r
        __builtin_nontemporal_store(acc, (f32x4*)(obase + (long)rg * 16 * B_));
        if (it < 63) { d0 = nd0; d1 = nd1; }
    }
}

extern "C" void kernel_launch(void* const* d_in, const int* in_sizes, int n_in,
                              void* d_out, int out_size, void* d_ws, size_t ws_size,
                              hipStream_t stream) {
    const float* pred    = (const float*)d_in[0];
    const float* imfs    = (const float*)d_in[1];
    const float* rev_w   = (const float*)d_in[2];
    const float* rev_b   = (const float*)d_in[3];
    const float* ca_w1   = (const float*)d_in[4];
    const float* ca_b1   = (const float*)d_in[5];
    const float* ca_w2   = (const float*)d_in[6];
    const float* ca_b2   = (const float*)d_in[7];
    const float* conv1_w = (const float*)d_in[8];
    const float* conv1_b = (const float*)d_in[9];
    const float* bn1_g   = (const float*)d_in[10];
    const float* bn1_b   = (const float*)d_in[11];
    const float* bn1_m   = (const float*)d_in[12];
    const float* bn1_v   = (const float*)d_in[13];
    const float* conv2_w = (const float*)d_in[14];
    const float* conv2_b = (const float*)d_in[15];
    const float* bn2_g   = (const float*)d_in[16];
    const float* bn2_b   = (const float*)d_in[17];
    const float* bn2_m   = (const float*)d_in[18];
    const float* bn2_v   = (const float*)d_in[19];

    float* out      = (float*)d_out;
    float* partials = (float*)d_ws;                    // 256 blocks x {s,s2} = 2KB
    bf16*  dhi      = (bf16*)((char*)d_ws + 2048);
    bf16*  whi      = dhi + NTOT;

    reduce_kernel<<<NRED, 256, 0, stream>>>(pred, imfs, partials);
    rows_kernel<<<512, 256, 0, stream>>>(pred, imfs, rev_w, rev_b, ca_w1, ca_b1,
                                         ca_w2, ca_b2, conv1_w, conv1_b,
                                         bn1_g, bn1_b, bn1_m, bn1_v,
                                         conv2_w, conv2_b, bn2_g, bn2_b, bn2_m, bn2_v,
                                         partials,
                                         out + OUT_W_OFF, out + OUT_DATA_OFF,
                                         out + OUT_XN_OFF, dhi, whi);
    gemm_kernel<<<1024, 256, 0, stream>>>(dhi, whi, out);
}